// Round 1
// baseline (184.024 us; speedup 1.0000x reference)
//
#include <hip/hip_runtime.h>

typedef __bf16 bf16x8 __attribute__((ext_vector_type(8)));
typedef float floatx4 __attribute__((ext_vector_type(4)));

__device__ __forceinline__ ushort f2bf(float f) {
  union { float f; unsigned u; } a; a.f = f;
  unsigned u = a.u;
  unsigned r = (u + 0x7FFFu + ((u >> 16) & 1u)) >> 16;
  return (ushort)r;
}

// ---------------- conversions ----------------
__global__ __launch_bounds__(256) void cvt_bf16_kernel(const float* __restrict__ src,
                                                       ushort* __restrict__ dst, int n4) {
  int i = blockIdx.x * 256 + threadIdx.x;
  if (i >= n4) return;
  float4 v = ((const float4*)src)[i];
  ushort4 o;
  o.x = f2bf(v.x); o.y = f2bf(v.y); o.z = f2bf(v.z); o.w = f2bf(v.w);
  ((ushort4*)dst)[i] = o;
}

// W: K x N (f32, row-major)  ->  WT: N x K (bf16, row-major), scaled
__global__ __launch_bounds__(256) void conv_T_kernel(const float* __restrict__ W,
                                                     ushort* __restrict__ WT,
                                                     int K, int N, float scale) {
  __shared__ float tile[32][33];
  int n0 = blockIdx.x * 32, k0 = blockIdx.y * 32;
  int xi = threadIdx.x & 31, yi = threadIdx.x >> 5;  // yi 0..7
  #pragma unroll
  for (int i = 0; i < 32; i += 8)
    tile[yi + i][xi] = W[(size_t)(k0 + yi + i) * N + n0 + xi];
  __syncthreads();
  #pragma unroll
  for (int i = 0; i < 32; i += 8)
    WT[(size_t)(n0 + yi + i) * K + k0 + xi] = f2bf(tile[xi][yi + i] * scale);
}

// ---------------- GEMM: C(MxN,f32) = A(MxK,bf16) * BT(NxK,bf16)^T ----------------
// block 256 threads = 4 waves (2x2), tile 128x128, BK=64
__global__ __launch_bounds__(256) void gemm_bf16_kernel(const ushort* __restrict__ A,
                                                        const ushort* __restrict__ BT,
                                                        float* __restrict__ C,
                                                        int M, int N, int K) {
  __shared__ __align__(16) ushort As[128][72];  // 64 + 8 pad (row stride 144B = 9*16)
  __shared__ __align__(16) ushort Bs[128][72];
  int tid = threadIdx.x;
  int lane = tid & 63, wid = tid >> 6;
  int wr = wid >> 1, wc = wid & 1;
  int m0 = blockIdx.x * 128, n0 = blockIdx.y * 128;
  int row = lane & 15, kseg = (lane >> 4) << 3;

  floatx4 acc[4][4];
  #pragma unroll
  for (int r = 0; r < 4; r++)
    #pragma unroll
    for (int c = 0; c < 4; c++)
      acc[r][c] = (floatx4){0.f, 0.f, 0.f, 0.f};

  int sm = tid >> 1;             // 0..127 (tile row)
  int sh = (tid & 1) * 32;       // 0 or 32 (bf16 elements)
  const ushort* ag = A + (size_t)(m0 + sm) * K + sh;
  const ushort* bg = BT + (size_t)(n0 + sm) * K + sh;

  for (int k0 = 0; k0 < K; k0 += 64) {
    const float4* agv = (const float4*)(ag + k0);
    const float4* bgv = (const float4*)(bg + k0);
    float4 a0 = agv[0], a1 = agv[1], a2 = agv[2], a3 = agv[3];
    float4 b0 = bgv[0], b1 = bgv[1], b2 = bgv[2], b3 = bgv[3];
    __syncthreads();  // previous iteration's readers done
    *(float4*)&As[sm][sh + 0]  = a0;
    *(float4*)&As[sm][sh + 8]  = a1;
    *(float4*)&As[sm][sh + 16] = a2;
    *(float4*)&As[sm][sh + 24] = a3;
    *(float4*)&Bs[sm][sh + 0]  = b0;
    *(float4*)&Bs[sm][sh + 8]  = b1;
    *(float4*)&Bs[sm][sh + 16] = b2;
    *(float4*)&Bs[sm][sh + 24] = b3;
    __syncthreads();
    #pragma unroll
    for (int kk = 0; kk < 64; kk += 32) {
      bf16x8 av[4], bv[4];
      #pragma unroll
      for (int r = 0; r < 4; r++)
        av[r] = *(const bf16x8*)&As[wr * 64 + r * 16 + row][kk + kseg];
      #pragma unroll
      for (int c = 0; c < 4; c++)
        bv[c] = *(const bf16x8*)&Bs[wc * 64 + c * 16 + row][kk + kseg];
      #pragma unroll
      for (int r = 0; r < 4; r++)
        #pragma unroll
        for (int c = 0; c < 4; c++)
          acc[r][c] = __builtin_amdgcn_mfma_f32_16x16x32_bf16(av[r], bv[c], acc[r][c], 0, 0, 0);
    }
  }

  int r4 = (lane >> 4) << 2;
  #pragma unroll
  for (int r = 0; r < 4; r++)
    #pragma unroll
    for (int c = 0; c < 4; c++) {
      int crow = m0 + wr * 64 + r * 16 + r4;
      int ccol = n0 + wc * 64 + c * 16 + (lane & 15);
      #pragma unroll
      for (int i = 0; i < 4; i++)
        C[(size_t)(crow + i) * N + ccol] = acc[r][c][i];
    }
}

// ---------------- decay gate (full f32) ----------------
// gamma[b][h][l] = exp(mean_d(log_sigmoid(kg)) / 16) + 1e-6
__global__ __launch_bounds__(256) void gate_kernel(const float* __restrict__ x,
                                                   const float* __restrict__ Wg1,
                                                   const float* __restrict__ Wg2,
                                                   float* __restrict__ gamma) {
  int rowi = blockIdx.x;          // b*1024 + l
  int b = rowi >> 10, l = rowi & 1023;
  int tid = threadIdx.x;
  __shared__ float part[16][17];
  __shared__ float tsh[16];

  // phase 1: t[16] = x_row @ Wg1
  {
    int j = tid & 15, slice = tid >> 4;  // 16 slices x 64 k
    const float* xr = x + (size_t)rowi * 1024 + slice * 64;
    float p = 0.f;
    #pragma unroll 4
    for (int kk = 0; kk < 64; kk++)
      p += xr[kk] * Wg1[(size_t)(slice * 64 + kk) * 16 + j];
    part[slice][j] = p;
  }
  __syncthreads();
  if (tid < 16) {
    float s = 0.f;
    #pragma unroll
    for (int i = 0; i < 16; i++) s += part[i][tid];
    tsh[tid] = s;
  }
  __syncthreads();

  // phase 2: kg[n] = t @ Wg2, log-sigmoid, per-head sum (head = n>>6)
  float ls0, ls1;
  {
    int n = tid;
    float kg = 0.f;
    #pragma unroll
    for (int j = 0; j < 16; j++) kg += tsh[j] * Wg2[j * 512 + n];
    ls0 = (kg >= 0.f) ? -log1pf(expf(-kg)) : (kg - log1pf(expf(kg)));
  }
  {
    int n = tid + 256;
    float kg = 0.f;
    #pragma unroll
    for (int j = 0; j < 16; j++) kg += tsh[j] * Wg2[j * 512 + n];
    ls1 = (kg >= 0.f) ? -log1pf(expf(-kg)) : (kg - log1pf(expf(kg)));
  }
  // wave w handles heads w (ls0) and w+4 (ls1); reduce over 64 lanes
  #pragma unroll
  for (int m = 32; m >= 1; m >>= 1) {
    ls0 += __shfl_xor(ls0, m);
    ls1 += __shfl_xor(ls1, m);
  }
  if ((tid & 63) == 0) {
    int w = tid >> 6;
    gamma[(size_t)(b * 8 + w) * 1024 + l]       = expf(ls0 * (1.f / 1024.f)) + 1e-6f;
    gamma[(size_t)(b * 8 + w + 4) * 1024 + l]   = expf(ls1 * (1.f / 1024.f)) + 1e-6f;
  }
}

// ---------------- recurrent scan, d-split x8 ----------------
// grid 128: block = bh*8 + dg; 128 threads (one per e)
__global__ __launch_bounds__(128) void scan_kernel(const float* __restrict__ Y,
                                                   const float* __restrict__ gamma,
                                                   float* __restrict__ part) {
  int blk = blockIdx.x;
  int bh = blk >> 3;       // 0..15
  int dg = blk & 7;        // 0..7
  int b = bh >> 3, h = bh & 7;
  int e = threadIdx.x;

  __shared__ __align__(16) float qs[64][8];
  __shared__ __align__(16) float ks[64][8];
  __shared__ __align__(16) float vs[64][128];
  __shared__ float gs[64];

  float s0 = 0, s1 = 0, s2 = 0, s3 = 0, s4 = 0, s5 = 0, s6 = 0, s7 = 0;

  const float* Yb = Y + (size_t)b * 1024 * 3072;
  int qcol = h * 64 + dg * 8;
  int kcol = 512 + qcol;
  int vcol = 1024 + h * 128;
  float* pout = part + ((size_t)(dg * 16 + bh) * 1024) * 128 + e;

  for (int c0 = 0; c0 < 1024; c0 += 64) {
    __syncthreads();
    {
      int l = threadIdx.x >> 1, hf = (threadIdx.x & 1) * 4;
      const float* base = Yb + (size_t)(c0 + l) * 3072;
      *(float4*)&qs[l][hf] = *(const float4*)(base + qcol + hf);
      *(float4*)&ks[l][hf] = *(const float4*)(base + kcol + hf);
    }
    #pragma unroll
    for (int i = 0; i < 16; i++) {
      int flat = (i * 128 + threadIdx.x) * 4;
      int l = flat >> 7, e4 = flat & 127;
      *(float4*)&vs[l][e4] = *(const float4*)(Yb + (size_t)(c0 + l) * 3072 + vcol + e4);
    }
    if (threadIdx.x < 64) gs[threadIdx.x] = gamma[(size_t)bh * 1024 + c0 + threadIdx.x];
    __syncthreads();

    for (int t = 0; t < 64; t++) {
      float g = gs[t];
      float vv = vs[t][e];
      float4 k0 = *(const float4*)&ks[t][0];
      float4 k1 = *(const float4*)&ks[t][4];
      float4 q0 = *(const float4*)&qs[t][0];
      float4 q1 = *(const float4*)&qs[t][4];
      float acc;
      s0 = g * s0 + k0.x * vv; acc  = q0.x * s0;
      s1 = g * s1 + k0.y * vv; acc += q0.y * s1;
      s2 = g * s2 + k0.z * vv; acc += q0.z * s2;
      s3 = g * s3 + k0.w * vv; acc += q0.w * s3;
      s4 = g * s4 + k1.x * vv; acc += q1.x * s4;
      s5 = g * s5 + k1.y * vv; acc += q1.y * s5;
      s6 = g * s6 + k1.z * vv; acc += q1.z * s6;
      s7 = g * s7 + k1.w * vv; acc += q1.w * s7;
      pout[(size_t)(c0 + t) * 128] = acc;
    }
  }
}

// ---------------- LayerNorm + silu gate, emit bf16 ----------------
// grid 16384: block = bh*1024 + l; 128 threads (one per e)
__global__ __launch_bounds__(128) void ln_gate_kernel(const float* __restrict__ part,
                                                      const float* __restrict__ Y,
                                                      const float* __restrict__ bgp,
                                                      ushort* __restrict__ gout) {
  int blk = blockIdx.x;
  int bh = blk >> 10, l = blk & 1023;
  int b = bh >> 3, h = bh & 7;
  int e = threadIdx.x;

  float o = 0.f;
  #pragma unroll
  for (int dg = 0; dg < 8; dg++)
    o += part[((size_t)(dg * 16 + bh) * 1024 + l) * 128 + e];

  float s1 = o, s2 = o * o;
  #pragma unroll
  for (int m = 32; m >= 1; m >>= 1) {
    s1 += __shfl_xor(s1, m);
    s2 += __shfl_xor(s2, m);
  }
  __shared__ float red[4];
  int w = threadIdx.x >> 6;
  if ((threadIdx.x & 63) == 0) { red[w * 2] = s1; red[w * 2 + 1] = s2; }
  __syncthreads();
  float S1 = red[0] + red[2], S2 = red[1] + red[3];
  float mu = S1 * (1.f / 128.f);
  float var = S2 * (1.f / 128.f) - mu * mu;
  float y = (o - mu) * rsqrtf(var + 1e-5f);

  int col = h * 128 + e;
  float z = Y[((size_t)(b * 1024 + l)) * 3072 + 2048 + col] + bgp[col];
  float gv = z / (1.f + expf(-z));
  gout[((size_t)(b * 1024 + l)) * 1024 + col] = f2bf(y * gv);
}

// ---------------- launch ----------------
extern "C" void kernel_launch(void* const* d_in, const int* in_sizes, int n_in,
                              void* d_out, int out_size, void* d_ws, size_t ws_size,
                              hipStream_t stream) {
  const float* x    = (const float*)d_in[0];
  const float* Wq   = (const float*)d_in[1];
  const float* Wk   = (const float*)d_in[2];
  const float* Wg1  = (const float*)d_in[3];
  const float* Wg2  = (const float*)d_in[4];
  const float* Wv   = (const float*)d_in[5];
  const float* Wgp  = (const float*)d_in[6];
  const float* bgp  = (const float*)d_in[7];
  const float* Wout = (const float*)d_in[8];
  float* out = (float*)d_out;

  char* ws = (char*)d_ws;
  float*  Y      = (float*)(ws + 0);                       // 2048*3072*4  = 25165824
  float*  part   = (float*)(ws + 25165824);                // 8*16*1024*128*4 = 67108864
  float*  gamma  = (float*)(ws + 92274688);                // 16*1024*4 = 65536
  ushort* xb     = (ushort*)(ws + 92340224);               // 2048*1024*2 = 4194304
  ushort* WcatT  = (ushort*)(ws + 96534528);               // 3072*1024*2 = 6291456
  ushort* WoutT  = (ushort*)(ws + 102825984);              // 1024*1024*2 = 2097152
  ushort* gout   = (ushort*)(ws + 104923136);              // 2048*1024*2 = 4194304
  // total 109117440 bytes

  // conversions
  cvt_bf16_kernel<<<2048, 256, 0, stream>>>(x, xb, 2048 * 1024 / 4);
  conv_T_kernel<<<dim3(16, 32), 256, 0, stream>>>(Wq,  WcatT + (size_t)0 * 1024,    1024, 512,  1.0f);
  conv_T_kernel<<<dim3(16, 32), 256, 0, stream>>>(Wk,  WcatT + (size_t)512 * 1024,  1024, 512,  0.125f);
  conv_T_kernel<<<dim3(32, 32), 256, 0, stream>>>(Wv,  WcatT + (size_t)1024 * 1024, 1024, 1024, 1.0f);
  conv_T_kernel<<<dim3(32, 32), 256, 0, stream>>>(Wgp, WcatT + (size_t)2048 * 1024, 1024, 1024, 1.0f);
  conv_T_kernel<<<dim3(32, 32), 256, 0, stream>>>(Wout, WoutT,                      1024, 1024, 1.0f);

  // decay gate (f32)
  gate_kernel<<<2048, 256, 0, stream>>>(x, Wg1, Wg2, gamma);

  // fused projections: Y = xb @ [Wq|Wk*s|Wv|Wgp]
  gemm_bf16_kernel<<<dim3(16, 24), 256, 0, stream>>>(xb, WcatT, Y, 2048, 3072, 1024);

  // recurrent scan (d-split x 8)
  scan_kernel<<<128, 128, 0, stream>>>(Y, gamma, part);

  // LN + silu gate -> bf16
  ln_gate_kernel<<<16384, 128, 0, stream>>>(part, Y, bgp, gout);

  // output projection
  gemm_bf16_kernel<<<dim3(16, 8), 256, 0, stream>>>(gout, WoutT, out, 2048, 1024, 1024);
}